// Round 13
// baseline (1929.607 us; speedup 1.0000x reference)
//
#include <hip/hip_runtime.h>
#include <hip/hip_bf16.h>

#define N_PTS 262144
#define STEP_LEN 0.0016914558667664818f

using f32x4 = __attribute__((ext_vector_type(4))) float;
using s8 = __attribute__((ext_vector_type(8))) short;

__device__ __forceinline__ float bf2f(short s) {
    union { unsigned int u; float f; } v;
    v.u = ((unsigned int)(unsigned short)s) << 16;
    return v.f;
}
__device__ __forceinline__ short f2bf(float f) {
    __hip_bfloat16 h = __float2bfloat16(f);
    return *reinterpret_cast<short*>(&h);
}

// ---- workspace: trunk = 60 contiguous 16KB k-step blocks [ks][nt16][lane][8],
// then C1G (4 blocks), C1DE+WSIG+WC2+pad (1 block). Total 65 x 16KB = 1.04 MB.
//   n = nt*16 + (lane&15);  k-slot = ks*32 + perm(hi,j)
// hidden perm (acc->B-frag): f = ks*32 + (j>>2)*16 + hi*4 + (j&3)
// pe-input k-steps: f = ks*32 + hi*8 + j (identity)
#define OFF_W1    0
#define OFF_L1H0  16384
#define OFF_W2    212992
#define OFF_L2H0  294912
#define OFF_C1G   491520    // [8ks][8nt][lane][8]
#define OFF_C1DE  524288    // [8nt][lane][8]
#define OFF_WSIG  528384    // [8ks][4hi][8j]
#define OFF_WC2   528640    // [3ch][4ks][4hi][8j]
#define WS_ELEMS  532480    // padded to 65*16KB

__device__ __forceinline__ float hid_val(const float* __restrict__ W, int e) {
    int j = e & 7, lane = (e >> 3) & 63, nt = (e >> 9) & 15, ks = e >> 13;
    int n = nt * 16 + (lane & 15), hi = lane >> 4;
    int f = ks * 32 + ((j >> 2) << 4) + hi * 4 + (j & 3);
    return W[n * 256 + f];
}

__global__ void prep_weights(const float* __restrict__ w1_in,
                             const float* __restrict__ w1_h,
                             const float* __restrict__ w2_in,
                             const float* __restrict__ w2_h,
                             const float* __restrict__ w_c1,
                             const float* __restrict__ w_sigma,
                             const float* __restrict__ w_c2,
                             __hip_bfloat16* __restrict__ ws) {
    int i = blockIdx.x * blockDim.x + threadIdx.x;
    if (i >= WS_ELEMS) return;
    float v;
    if (i < OFF_L1H0) {              // W1: pe input, identity k-map
        int e = i;
        int j = e & 7, lane = (e >> 3) & 63, nt = (e >> 9) & 15, ks = e >> 13;
        int n = nt * 16 + (lane & 15), hi = lane >> 4;
        int f = ks * 32 + hi * 8 + j;
        v = (f < 63) ? w1_in[n * 63 + f] : 0.f;
    } else if (i < OFF_W2) {         // 3x L1 hidden, permuted k-map
        int e = i - OFF_L1H0; int sub = e >> 16; e &= 65535;
        v = hid_val(w1_h + sub * 65536, e);
    } else if (i < OFF_L2H0) {       // W2: h part permuted, pe part identity
        int e = i - OFF_W2;
        int j = e & 7, lane = (e >> 3) & 63, nt = (e >> 9) & 15, ks = e >> 13;
        int n = nt * 16 + (lane & 15), hi = lane >> 4;
        if (ks < 8) {
            int f = ks * 32 + ((j >> 2) << 4) + hi * 4 + (j & 3);
            v = w2_in[n * 319 + f];
        } else {
            int pf = (ks - 8) * 32 + hi * 8 + j;
            v = (pf < 63) ? w2_in[n * 319 + 256 + pf] : 0.f;
        }
    } else if (i < OFF_C1G) {        // 3x L2 hidden, permuted k-map
        int e = i - OFF_L2H0; int sub = e >> 16; e &= 65535;
        v = hid_val(w2_h + sub * 65536, e);
    } else if (i < OFF_C1DE) {       // color1 g-part, permuted, 8 nt
        int e = i - OFF_C1G;
        int j = e & 7, lane = (e >> 3) & 63, nt = (e >> 9) & 7, ks = e >> 12;
        int n = nt * 16 + (lane & 15), hi = lane >> 4;
        int f = ks * 32 + ((j >> 2) << 4) + hi * 4 + (j & 3);
        v = w_c1[n * 283 + f];
    } else if (i < OFF_WSIG) {       // color1 de-part, identity k-map
        int e = i - OFF_C1DE;
        int j = e & 7, lane = (e >> 3) & 63, nt = (e >> 9) & 7;
        int n = nt * 16 + (lane & 15), hi = lane >> 4;
        int k = 256 + hi * 8 + j;
        v = (k < 283) ? w_c1[n * 283 + k] : 0.f;
    } else if (i < OFF_WC2) {        // sigma weights, permuted
        int e = i - OFF_WSIG;
        int j = e & 7, hi = (e >> 3) & 3, ks = e >> 5;
        int f = ks * 32 + ((j >> 2) << 4) + hi * 4 + (j & 3);
        v = w_sigma[f];
    } else if (i < 529024) {         // color2 weights, permuted
        int e = i - OFF_WC2;
        int j = e & 7, hi = (e >> 3) & 3, ks = (e >> 5) & 3, ch = e >> 7;
        int f = ks * 32 + ((j >> 2) << 4) + hi * 4 + (j & 3);
        v = w_c2[ch * 128 + f];
    } else {
        v = 0.f;                     // pad to 16KB multiple
    }
    ws[i] = __float2bfloat16(v);
}

__device__ __forceinline__ float enc3(int f, float x0, float x1, float x2) {
    if (f < 3) return (f == 0) ? x0 : ((f == 1) ? x1 : x2);
    if (f < 33) {
        int q = f - 3; int c = q / 10, o = q % 10;
        float xc = (c == 0) ? x0 : ((c == 1) ? x1 : x2);
        return __sinf(xc * (float)(1 << o));
    }
    if (f < 63) {
        int q = f - 33; int c = q / 10, o = q % 10;
        float xc = (c == 0) ? x0 : ((c == 1) ? x1 : x2);
        return __cosf(xc * (float)(1 << o));
    }
    return 0.f;
}

#define MFMA16 __builtin_amdgcn_mfma_f32_16x16x32_bf16

// stage one 16KB k-step block: 8 waves x 2 x global_load_lds(16B) (2KB/wave)
#define STAGE2(BYTEOFF, DBUF) do { \
    const char* _src = wsB + (long)(BYTEOFF) + wid * 2048 + lane * 16; \
    char* _dst = (DBUF) + wid * 2048; \
    __builtin_amdgcn_global_load_lds((const unsigned int*)(_src),        (unsigned int*)(_dst),        16, 0, 0); \
    __builtin_amdgcn_global_load_lds((const unsigned int*)(_src + 1024), (unsigned int*)(_dst + 1024), 16, 0, 0); \
} while (0)

// one trunk k-step: stage s+2, 32 MFMAs from ring buffer
#define WKSTEP(RDBUF, STGOFF, WRBUF, A0, A1, FIRSTV) do { \
    STAGE2(STGOFF, WRBUF); \
    __builtin_amdgcn_s_setprio(1); \
    _Pragma("unroll") \
    for (int nt = 0; nt < 16; ++nt) { \
        const s8 w = *(const s8*)((RDBUF) + nt * 1024 + lane * 16); \
        acc[nt][0] = MFMA16(w, (A0), (FIRSTV) ? Z : acc[nt][0], 0, 0, 0); \
        acc[nt][1] = MFMA16(w, (A1), (FIRSTV) ? Z : acc[nt][1], 0, 0, 0); \
    } \
    __builtin_amdgcn_s_setprio(0); \
} while (0)

// counted-vmcnt barrier: 2 newest loads (next-next stage) stay in flight
#define KBAR2 do { asm volatile("s_waitcnt vmcnt(2)" ::: "memory"); \
                   __builtin_amdgcn_s_barrier(); } while (0)
#define KBAR0 do { asm volatile("s_waitcnt vmcnt(0)" ::: "memory"); \
                   __builtin_amdgcn_s_barrier(); } while (0)

// acc -> next-layer act frags (bias from LDS -> lgkmcnt only, keeps vmcnt pure)
#define CONVERTL(BOFF) do { \
    _Pragma("unroll") \
    for (int nt = 0; nt < 16; ++nt) { \
        const f32x4 b4 = *(const f32x4*)(biasL + (((BOFF) + nt * 16 + hi4) << 2)); \
        _Pragma("unroll") \
        for (int r = 0; r < 4; ++r) { \
            actA[nt >> 1][((nt & 1) << 2) | r] = f2bf(fmaxf(acc[nt][0][r] + b4[r], 0.f)); \
            actB[nt >> 1][((nt & 1) << 2) | r] = f2bf(fmaxf(acc[nt][1][r] + b4[r], 0.f)); \
        } } } while (0)

// color k-step: 2 color-ks (8 nt each) from one 16KB buffer
#define CKSTEP(RDBUF, KS, FIRSTV) do { \
    __builtin_amdgcn_s_setprio(1); \
    _Pragma("unroll") \
    for (int nt = 0; nt < 8; ++nt) { \
        const s8 w = *(const s8*)((RDBUF) + nt * 1024 + lane * 16); \
        acc[nt][0] = MFMA16(w, actA[KS], (FIRSTV) ? Z : acc[nt][0], 0, 0, 0); \
        acc[nt][1] = MFMA16(w, actB[KS], (FIRSTV) ? Z : acc[nt][1], 0, 0, 0); \
    } \
    _Pragma("unroll") \
    for (int nt = 0; nt < 8; ++nt) { \
        const s8 w = *(const s8*)((RDBUF) + 8192 + nt * 1024 + lane * 16); \
        acc[nt][0] = MFMA16(w, actA[(KS) + 1], acc[nt][0], 0, 0, 0); \
        acc[nt][1] = MFMA16(w, actB[(KS) + 1], acc[nt][1], 0, 0, 0); \
    } \
    __builtin_amdgcn_s_setprio(0); \
} while (0)

__global__ __launch_bounds__(512, 4) void nerf_fused(
    const float* __restrict__ pos, const float* __restrict__ dir,
    const __hip_bfloat16* __restrict__ ws,
    const float* __restrict__ b1_in, const float* __restrict__ b1_h,
    const float* __restrict__ b2_in, const float* __restrict__ b2_h,
    const float* __restrict__ b_sigma, const float* __restrict__ b_c1,
    const float* __restrict__ b_c2,
    float* __restrict__ out) {

    // 4 x 16KB weight ring + 8.7KB bias table = 74.2KB -> 2 blocks/CU (16 waves)
    __shared__ __align__(16) char Lds[74240];
    char* const S0 = Lds;
    char* const S1 = Lds + 16384;
    char* const S2 = Lds + 32768;
    char* const S3 = Lds + 49152;
    char* const biasL = Lds + 65536;

    const int t = threadIdx.x;
    const int lane = t & 63;
    const int wid = t >> 6;            // 0..7
    const int hi = lane >> 4;
    const int col = lane & 15;
    const int hi4 = hi * 4;
    const int row0 = blockIdx.x * 256;
    const int gA = row0 + wid * 32 + col;
    const int gB = gA + 16;
    const char* wsB = (const char*)ws;

    // ---- biases -> LDS (f32): [b1_in|b1_h*3|b2_in|b2_h*3|b_c1] = 2176 ----
    for (int i = t; i < 2176; i += 512) {
        float v;
        if (i < 256) v = b1_in[i];
        else if (i < 1024) v = b1_h[i - 256];
        else if (i < 1280) v = b2_in[i - 1024];
        else if (i < 2048) v = b2_h[i - 1280];
        else v = b_c1[i - 2048];
        *(float*)(biasL + i * 4) = v;
    }

    // ---- positional encoding frags ----
    s8 peA0, peA1, peB0, peB1;
    {
        float xa0 = pos[gA*3], xa1 = pos[gA*3+1], xa2 = pos[gA*3+2];
        float xb0 = pos[gB*3], xb1 = pos[gB*3+1], xb2 = pos[gB*3+2];
#pragma unroll
        for (int j = 0; j < 8; ++j) {
            int f0 = hi * 8 + j, f1 = 32 + hi * 8 + j;
            peA0[j] = f2bf(enc3(f0, xa0, xa1, xa2));
            peA1[j] = f2bf(enc3(f1, xa0, xa1, xa2));
            peB0[j] = f2bf(enc3(f0, xb0, xb1, xb2));
            peB1[j] = f2bf(enc3(f1, xb0, xb1, xb2));
        }
    }

    f32x4 acc[16][2];
    s8 actA[8], actB[8];
    const f32x4 Z = {0.f, 0.f, 0.f, 0.f};

    // ---- prologue: stage s0,s1; drain s0 + LDS writes; keep s1 in flight ----
    STAGE2(0L, S0);
    STAGE2(16384L, S1);
    asm volatile("s_waitcnt vmcnt(2) lgkmcnt(0)" ::: "memory");
    __builtin_amdgcn_s_barrier();

    // ---- W1 (s0,s1): K=64 from pe ----
    WKSTEP(S0, 2L*16384, S2, peA0, peB0, 1); KBAR2;
    WKSTEP(S1, 3L*16384, S3, peA1, peB1, 0); CONVERTL(0); KBAR2;

    // ---- 3x L1 hidden (phase 2) ----
#pragma unroll 1
    for (int l = 0; l < 3; ++l) {
        const long lb = 65536L + (long)l * 131072;   // stage byte base (s+2)
        const int bo = 256 + (l << 8);
        WKSTEP(S2, lb,            S0, actA[0], actB[0], 1); KBAR2;
        WKSTEP(S3, lb + 16384,    S1, actA[1], actB[1], 0); KBAR2;
        WKSTEP(S0, lb + 2*16384,  S2, actA[2], actB[2], 0); KBAR2;
        WKSTEP(S1, lb + 3*16384,  S3, actA[3], actB[3], 0); KBAR2;
        WKSTEP(S2, lb + 4*16384,  S0, actA[4], actB[4], 0); KBAR2;
        WKSTEP(S3, lb + 5*16384,  S1, actA[5], actB[5], 0); KBAR2;
        WKSTEP(S0, lb + 6*16384,  S2, actA[6], actB[6], 0); KBAR2;
        WKSTEP(S1, lb + 7*16384,  S3, actA[7], actB[7], 0); CONVERTL(bo); KBAR2;
    }

    // ---- W2 (s26..35): K=320 = 8 act ks + 2 pe ks ----
    WKSTEP(S2, 28L*16384, S0, actA[0], actB[0], 1); KBAR2;
    WKSTEP(S3, 29L*16384, S1, actA[1], actB[1], 0); KBAR2;
    WKSTEP(S0, 30L*16384, S2, actA[2], actB[2], 0); KBAR2;
    WKSTEP(S1, 31L*16384, S3, actA[3], actB[3], 0); KBAR2;
    WKSTEP(S2, 32L*16384, S0, actA[4], actB[4], 0); KBAR2;
    WKSTEP(S3, 33L*16384, S1, actA[5], actB[5], 0); KBAR2;
    WKSTEP(S0, 34L*16384, S2, actA[6], actB[6], 0); KBAR2;
    WKSTEP(S1, 35L*16384, S3, actA[7], actB[7], 0); KBAR2;
    WKSTEP(S2, 36L*16384, S0, peA0,    peB0,    0); KBAR2;
    WKSTEP(S3, 37L*16384, S1, peA1,    peB1,    0); CONVERTL(1024); KBAR2;

    // ---- 3x L2 hidden (phase 0) ----
#pragma unroll 1
    for (int l = 0; l < 3; ++l) {
        const long lb = (long)(38 + (l << 3)) * 16384;
        const int bo = 1280 + (l << 8);
        WKSTEP(S0, lb,            S2, actA[0], actB[0], 1); KBAR2;
        WKSTEP(S1, lb + 16384,    S3, actA[1], actB[1], 0); KBAR2;
        WKSTEP(S2, lb + 2*16384,  S0, actA[2], actB[2], 0); KBAR2;
        WKSTEP(S3, lb + 3*16384,  S1, actA[3], actB[3], 0); KBAR2;
        WKSTEP(S0, lb + 4*16384,  S2, actA[4], actB[4], 0); KBAR2;
        WKSTEP(S1, lb + 5*16384,  S3, actA[5], actB[5], 0); KBAR2;
        WKSTEP(S2, lb + 6*16384,  S0, actA[6], actB[6], 0); KBAR2;
        WKSTEP(S3, lb + 7*16384,  S1, actA[7], actB[7], 0); CONVERTL(bo); KBAR2;
    }
    // g in actA/actB. Ring state: s60 in S0 (landed), s61 in S1 (in flight<=2).

    // ---- sigma head (keep alpha in regs; store in epilogue) ----
    float alphaA, alphaB, srA, srB;
    {
        float sA = 0.f, sB = 0.f;
#pragma unroll
        for (int ks = 0; ks < 8; ++ks) {
            const s8 wv = *(const s8*)(wsB + (OFF_WSIG + ks * 32 + hi * 8) * 2);
#pragma unroll
            for (int j = 0; j < 8; ++j) {
                sA += bf2f(actA[ks][j]) * bf2f(wv[j]);
                sB += bf2f(actB[ks][j]) * bf2f(wv[j]);
            }
        }
        sA += __shfl_xor(sA, 16); sA += __shfl_xor(sA, 32);
        sB += __shfl_xor(sB, 16); sB += __shfl_xor(sB, 32);
        srA = sA + b_sigma[0]; srB = sB + b_sigma[0];
        alphaA = 1.f - __expf(-fmaxf(srA, 0.f) * STEP_LEN);
        alphaB = 1.f - __expf(-fmaxf(srB, 0.f) * STEP_LEN);
    }

    // ---- dir-encoding frags (26 dims + sigma at d=26, zero pad) ----
    s8 deA, deB;
    {
        float uA0 = (dir[gA*3+0] + 1.f) * 0.5f;
        float uA1 = (dir[gA*3+1] + 1.f) * 0.5f;
        float uA2 = (dir[gA*3+2] + 1.f) * 0.5f;
        float uB0 = (dir[gB*3+0] + 1.f) * 0.5f;
        float uB1 = (dir[gB*3+1] + 1.f) * 0.5f;
        float uB2 = (dir[gB*3+2] + 1.f) * 0.5f;
#pragma unroll
        for (int j = 0; j < 8; ++j) {
            int d = hi * 8 + j;
            float vA, vB;
            if (d < 13) {
                int c = d / 5, o = d % 5; float s = (float)(1 << o);
                vA = __sinf(((c == 0) ? uA0 : (c == 1) ? uA1 : uA2) * s);
                vB = __sinf(((c == 0) ? uB0 : (c == 1) ? uB1 : uB2) * s);
            } else if (d < 26) {
                int q = d - 13; int c = q / 5, o = q % 5; float s = (float)(1 << o);
                vA = __cosf(((c == 0) ? uA0 : (c == 1) ? uA1 : uA2) * s);
                vB = __cosf(((c == 0) ? uB0 : (c == 1) ? uB1 : uB2) * s);
            } else if (d == 26) {
                vA = srA; vB = srB;
            } else {
                vA = 0.f; vB = 0.f;
            }
            deA[j] = f2bf(vA); deB[j] = f2bf(vB);
        }
    }

    // ---- color layer 1: 4 C1G k-steps + de k-step (ring continues) ----
    STAGE2(62L*16384, S2); CKSTEP(S0, 0, 1); KBAR2;
    STAGE2(63L*16384, S3); CKSTEP(S1, 2, 0); KBAR2;
    STAGE2(64L*16384, S0); CKSTEP(S2, 4, 0); KBAR2;
    CKSTEP(S3, 6, 0); KBAR0;
    {   // de part from S0 (first 8KB of s64)
        __builtin_amdgcn_s_setprio(1);
#pragma unroll
        for (int nt = 0; nt < 8; ++nt) {
            const s8 w = *(const s8*)(S0 + nt * 1024 + lane * 16);
            acc[nt][0] = MFMA16(w, deA, acc[nt][0], 0, 0, 0);
            acc[nt][1] = MFMA16(w, deB, acc[nt][1], 0, 0, 0);
        }
        __builtin_amdgcn_s_setprio(0);
    }

    // ---- c1 frags (bias from LDS) ----
    s8 c1A[4], c1B[4];
#pragma unroll
    for (int nt = 0; nt < 8; ++nt) {
        const f32x4 b4 = *(const f32x4*)(biasL + ((2048 + nt * 16 + hi4) << 2));
#pragma unroll
        for (int r = 0; r < 4; ++r) {
            c1A[nt >> 1][((nt & 1) << 2) | r] = f2bf(fmaxf(acc[nt][0][r] + b4[r], 0.f));
            c1B[nt >> 1][((nt & 1) << 2) | r] = f2bf(fmaxf(acc[nt][1][r] + b4[r], 0.f));
        }
    }

    // ---- color layer 2 + sigmoid; all global stores here ----
#pragma unroll
    for (int ch = 0; ch < 3; ++ch) {
        float rA = 0.f, rB = 0.f;
#pragma unroll
        for (int ks = 0; ks < 4; ++ks) {
            const s8 wv = *(const s8*)(wsB + (OFF_WC2 + (ch * 4 + ks) * 32 + hi * 8) * 2);
#pragma unroll
            for (int j = 0; j < 8; ++j) {
                rA += bf2f(c1A[ks][j]) * bf2f(wv[j]);
                rB += bf2f(c1B[ks][j]) * bf2f(wv[j]);
            }
        }
        rA += __shfl_xor(rA, 16); rA += __shfl_xor(rA, 32);
        rB += __shfl_xor(rB, 16); rB += __shfl_xor(rB, 32);
        if (hi == 0) {
            out[gA * 3 + ch] = 1.f / (1.f + __expf(-(rA + b_c2[ch])));
            out[gB * 3 + ch] = 1.f / (1.f + __expf(-(rB + b_c2[ch])));
        }
    }
    if (hi == 0) {
        out[3 * N_PTS + gA] = alphaA;
        out[3 * N_PTS + gB] = alphaB;
    }
}

extern "C" void kernel_launch(void* const* d_in, const int* in_sizes, int n_in,
                              void* d_out, int out_size, void* d_ws, size_t ws_size,
                              hipStream_t stream) {
    const float* position = (const float*)d_in[0];
    const float* direction = (const float*)d_in[1];
    const float* w1_in = (const float*)d_in[2];
    const float* b1_in = (const float*)d_in[3];
    const float* w1_h  = (const float*)d_in[4];
    const float* b1_h  = (const float*)d_in[5];
    const float* w2_in = (const float*)d_in[6];
    const float* b2_in = (const float*)d_in[7];
    const float* w2_h  = (const float*)d_in[8];
    const float* b2_h  = (const float*)d_in[9];
    const float* w_sigma = (const float*)d_in[10];
    const float* b_sigma = (const float*)d_in[11];
    const float* w_c1  = (const float*)d_in[12];
    const float* b_c1  = (const float*)d_in[13];
    const float* w_c2  = (const float*)d_in[14];
    const float* b_c2  = (const float*)d_in[15];
    float* out = (float*)d_out;
    __hip_bfloat16* ws = (__hip_bfloat16*)d_ws;

    prep_weights<<<(WS_ELEMS + 255) / 256, 256, 0, stream>>>(
        w1_in, w1_h, w2_in, w2_h, w_c1, w_sigma, w_c2, ws);

    nerf_fused<<<N_PTS / 256, 512, 0, stream>>>(
        position, direction, ws,
        b1_in, b1_h, b2_in, b2_h,
        b_sigma, b_c1, b_c2, out);
}

// Round 14
// 240.037 us; speedup vs baseline: 8.0388x; 8.0388x over previous
//
#include <hip/hip_runtime.h>
#include <hip/hip_bf16.h>

#define N_PTS 262144
#define STEP_LEN 0.0016914558667664818f

using f32x4 = __attribute__((ext_vector_type(4))) float;
using s8 = __attribute__((ext_vector_type(8))) short;

__device__ __forceinline__ float bf2f(short s) {
    union { unsigned int u; float f; } v;
    v.u = ((unsigned int)(unsigned short)s) << 16;
    return v.f;
}
__device__ __forceinline__ short f2bf(float f) {
    __hip_bfloat16 h = __float2bfloat16(f);
    return *reinterpret_cast<short*>(&h);
}

// ---- workspace: trunk = 60 contiguous 16KB k-step blocks [ks][nt16][lane][8],
// then C1G (4 blocks), C1DE+WSIG+WC2+pad (1 block). Total 65 x 16KB = 1.04 MB.
//   n = nt*16 + (lane&15);  k-slot = ks*32 + perm(hi,j)
// hidden perm (acc->B-frag): f = ks*32 + (j>>2)*16 + hi*4 + (j&3)
// pe-input k-steps: f = ks*32 + hi*8 + j (identity)
#define OFF_W1    0
#define OFF_L1H0  16384
#define OFF_W2    212992
#define OFF_L2H0  294912
#define OFF_C1G   491520    // [8ks][8nt][lane][8]
#define OFF_C1DE  524288    // [8nt][lane][8]
#define OFF_WSIG  528384    // [8ks][4hi][8j]
#define OFF_WC2   528640    // [3ch][4ks][4hi][8j]
#define WS_ELEMS  532480    // padded to 65*16KB

__device__ __forceinline__ float hid_val(const float* __restrict__ W, int e) {
    int j = e & 7, lane = (e >> 3) & 63, nt = (e >> 9) & 15, ks = e >> 13;
    int n = nt * 16 + (lane & 15), hi = lane >> 4;
    int f = ks * 32 + ((j >> 2) << 4) + hi * 4 + (j & 3);
    return W[n * 256 + f];
}

__global__ void prep_weights(const float* __restrict__ w1_in,
                             const float* __restrict__ w1_h,
                             const float* __restrict__ w2_in,
                             const float* __restrict__ w2_h,
                             const float* __restrict__ w_c1,
                             const float* __restrict__ w_sigma,
                             const float* __restrict__ w_c2,
                             __hip_bfloat16* __restrict__ ws) {
    int i = blockIdx.x * blockDim.x + threadIdx.x;
    if (i >= WS_ELEMS) return;
    float v;
    if (i < OFF_L1H0) {              // W1: pe input, identity k-map
        int e = i;
        int j = e & 7, lane = (e >> 3) & 63, nt = (e >> 9) & 15, ks = e >> 13;
        int n = nt * 16 + (lane & 15), hi = lane >> 4;
        int f = ks * 32 + hi * 8 + j;
        v = (f < 63) ? w1_in[n * 63 + f] : 0.f;
    } else if (i < OFF_W2) {         // 3x L1 hidden, permuted k-map
        int e = i - OFF_L1H0; int sub = e >> 16; e &= 65535;
        v = hid_val(w1_h + sub * 65536, e);
    } else if (i < OFF_L2H0) {       // W2: h part permuted, pe part identity
        int e = i - OFF_W2;
        int j = e & 7, lane = (e >> 3) & 63, nt = (e >> 9) & 15, ks = e >> 13;
        int n = nt * 16 + (lane & 15), hi = lane >> 4;
        if (ks < 8) {
            int f = ks * 32 + ((j >> 2) << 4) + hi * 4 + (j & 3);
            v = w2_in[n * 319 + f];
        } else {
            int pf = (ks - 8) * 32 + hi * 8 + j;
            v = (pf < 63) ? w2_in[n * 319 + 256 + pf] : 0.f;
        }
    } else if (i < OFF_C1G) {        // 3x L2 hidden, permuted k-map
        int e = i - OFF_L2H0; int sub = e >> 16; e &= 65535;
        v = hid_val(w2_h + sub * 65536, e);
    } else if (i < OFF_C1DE) {       // color1 g-part, permuted, 8 nt
        int e = i - OFF_C1G;
        int j = e & 7, lane = (e >> 3) & 63, nt = (e >> 9) & 7, ks = e >> 12;
        int n = nt * 16 + (lane & 15), hi = lane >> 4;
        int f = ks * 32 + ((j >> 2) << 4) + hi * 4 + (j & 3);
        v = w_c1[n * 283 + f];
    } else if (i < OFF_WSIG) {       // color1 de-part, identity k-map
        int e = i - OFF_C1DE;
        int j = e & 7, lane = (e >> 3) & 63, nt = (e >> 9) & 7;
        int n = nt * 16 + (lane & 15), hi = lane >> 4;
        int k = 256 + hi * 8 + j;
        v = (k < 283) ? w_c1[n * 283 + k] : 0.f;
    } else if (i < OFF_WC2) {        // sigma weights, permuted
        int e = i - OFF_WSIG;
        int j = e & 7, hi = (e >> 3) & 3, ks = e >> 5;
        int f = ks * 32 + ((j >> 2) << 4) + hi * 4 + (j & 3);
        v = w_sigma[f];
    } else if (i < 529024) {         // color2 weights, permuted
        int e = i - OFF_WC2;
        int j = e & 7, hi = (e >> 3) & 3, ks = (e >> 5) & 3, ch = e >> 7;
        int f = ks * 32 + ((j >> 2) << 4) + hi * 4 + (j & 3);
        v = w_c2[ch * 128 + f];
    } else {
        v = 0.f;                     // pad to 16KB multiple
    }
    ws[i] = __float2bfloat16(v);
}

__device__ __forceinline__ float enc3(int f, float x0, float x1, float x2) {
    if (f < 3) return (f == 0) ? x0 : ((f == 1) ? x1 : x2);
    if (f < 33) {
        int q = f - 3; int c = q / 10, o = q % 10;
        float xc = (c == 0) ? x0 : ((c == 1) ? x1 : x2);
        return __sinf(xc * (float)(1 << o));
    }
    if (f < 63) {
        int q = f - 33; int c = q / 10, o = q % 10;
        float xc = (c == 0) ? x0 : ((c == 1) ? x1 : x2);
        return __cosf(xc * (float)(1 << o));
    }
    return 0.f;
}

#define MFMA16 __builtin_amdgcn_mfma_f32_16x16x32_bf16

// stage one 16KB k-step block: 4 waves x 4 x global_load_lds(16B)
#define STAGE4(BYTEOFF, DBUF) do { \
    const char* _src = wsB + (long)(BYTEOFF) + wid * 4096 + lane * 16; \
    char* _dst = (DBUF) + wid * 4096; \
    __builtin_amdgcn_global_load_lds((const unsigned int*)(_src),        (unsigned int*)(_dst),        16, 0, 0); \
    __builtin_amdgcn_global_load_lds((const unsigned int*)(_src + 1024), (unsigned int*)(_dst + 1024), 16, 0, 0); \
    __builtin_amdgcn_global_load_lds((const unsigned int*)(_src + 2048), (unsigned int*)(_dst + 2048), 16, 0, 0); \
    __builtin_amdgcn_global_load_lds((const unsigned int*)(_src + 3072), (unsigned int*)(_dst + 3072), 16, 0, 0); \
} while (0)

// one trunk k-step: stage s+2, 32 MFMAs from ring buffer
#define WKSTEP(RDBUF, STGOFF, WRBUF, A0, A1, FIRSTV) do { \
    STAGE4(STGOFF, WRBUF); \
    __builtin_amdgcn_s_setprio(1); \
    _Pragma("unroll") \
    for (int nt = 0; nt < 16; ++nt) { \
        const s8 w = *(const s8*)((RDBUF) + nt * 1024 + lane * 16); \
        acc[nt][0] = MFMA16(w, (A0), (FIRSTV) ? Z : acc[nt][0], 0, 0, 0); \
        acc[nt][1] = MFMA16(w, (A1), (FIRSTV) ? Z : acc[nt][1], 0, 0, 0); \
    } \
    __builtin_amdgcn_s_setprio(0); \
} while (0)

// counted-vmcnt barrier: 4 newest loads (next-next stage) stay in flight
#define KBAR4 do { asm volatile("s_waitcnt vmcnt(4)" ::: "memory"); \
                   __builtin_amdgcn_s_barrier(); } while (0)
#define KBAR0 do { asm volatile("s_waitcnt vmcnt(0)" ::: "memory"); \
                   __builtin_amdgcn_s_barrier(); } while (0)

// acc -> next-layer act frags (bias from LDS -> lgkmcnt only, keeps vmcnt pure)
#define CONVERTL(BOFF) do { \
    _Pragma("unroll") \
    for (int nt = 0; nt < 16; ++nt) { \
        const f32x4 b4 = *(const f32x4*)(biasL + (((BOFF) + nt * 16 + hi4) << 2)); \
        _Pragma("unroll") \
        for (int r = 0; r < 4; ++r) { \
            actA[nt >> 1][((nt & 1) << 2) | r] = f2bf(fmaxf(acc[nt][0][r] + b4[r], 0.f)); \
            actB[nt >> 1][((nt & 1) << 2) | r] = f2bf(fmaxf(acc[nt][1][r] + b4[r], 0.f)); \
        } } } while (0)

// color k-step: 2 color-ks (8 nt each) from one 16KB buffer
#define CKSTEP(RDBUF, KS, FIRSTV) do { \
    __builtin_amdgcn_s_setprio(1); \
    _Pragma("unroll") \
    for (int nt = 0; nt < 8; ++nt) { \
        const s8 w = *(const s8*)((RDBUF) + nt * 1024 + lane * 16); \
        acc[nt][0] = MFMA16(w, actA[KS], (FIRSTV) ? Z : acc[nt][0], 0, 0, 0); \
        acc[nt][1] = MFMA16(w, actB[KS], (FIRSTV) ? Z : acc[nt][1], 0, 0, 0); \
    } \
    _Pragma("unroll") \
    for (int nt = 0; nt < 8; ++nt) { \
        const s8 w = *(const s8*)((RDBUF) + 8192 + nt * 1024 + lane * 16); \
        acc[nt][0] = MFMA16(w, actA[(KS) + 1], acc[nt][0], 0, 0, 0); \
        acc[nt][1] = MFMA16(w, actB[(KS) + 1], acc[nt][1], 0, 0, 0); \
    } \
    __builtin_amdgcn_s_setprio(0); \
} while (0)

__global__ __launch_bounds__(256, 2) void nerf_fused(
    const float* __restrict__ pos, const float* __restrict__ dir,
    const __hip_bfloat16* __restrict__ ws,
    const float* __restrict__ b1_in, const float* __restrict__ b1_h,
    const float* __restrict__ b2_in, const float* __restrict__ b2_h,
    const float* __restrict__ b_sigma, const float* __restrict__ b_c1,
    const float* __restrict__ b_c2,
    float* __restrict__ out) {

    // 4 x 16KB weight ring + 8.7KB bias table = 74.2KB -> 2 blocks/CU
    __shared__ __align__(16) char Lds[74240];
    char* const S0 = Lds;
    char* const S1 = Lds + 16384;
    char* const S2 = Lds + 32768;
    char* const S3 = Lds + 49152;
    char* const biasL = Lds + 65536;

    const int t = threadIdx.x;
    const int lane = t & 63;
    const int wid = t >> 6;
    const int hi = lane >> 4;
    const int col = lane & 15;
    const int hi4 = hi * 4;
    const int row0 = blockIdx.x * 128;
    const int gA = row0 + wid * 32 + col;
    const int gB = gA + 16;
    const char* wsB = (const char*)ws;

    // ---- biases -> LDS (f32): [b1_in|b1_h*3|b2_in|b2_h*3|b_c1] = 2176 ----
    for (int i = t; i < 2176; i += 256) {
        float v;
        if (i < 256) v = b1_in[i];
        else if (i < 1024) v = b1_h[i - 256];
        else if (i < 1280) v = b2_in[i - 1024];
        else if (i < 2048) v = b2_h[i - 1280];
        else v = b_c1[i - 2048];
        *(float*)(biasL + i * 4) = v;
    }

    // ---- positional encoding frags ----
    s8 peA0, peA1, peB0, peB1;
    {
        float xa0 = pos[gA*3], xa1 = pos[gA*3+1], xa2 = pos[gA*3+2];
        float xb0 = pos[gB*3], xb1 = pos[gB*3+1], xb2 = pos[gB*3+2];
#pragma unroll
        for (int j = 0; j < 8; ++j) {
            int f0 = hi * 8 + j, f1 = 32 + hi * 8 + j;
            peA0[j] = f2bf(enc3(f0, xa0, xa1, xa2));
            peA1[j] = f2bf(enc3(f1, xa0, xa1, xa2));
            peB0[j] = f2bf(enc3(f0, xb0, xb1, xb2));
            peB1[j] = f2bf(enc3(f1, xb0, xb1, xb2));
        }
    }

    f32x4 acc[16][2];
    s8 actA[8], actB[8];
    const f32x4 Z = {0.f, 0.f, 0.f, 0.f};

    // ---- prologue: stage s0,s1; drain LDS writes + all but newest 4 ----
    STAGE4(0L, S0);
    STAGE4(16384L, S1);
    asm volatile("s_waitcnt vmcnt(4) lgkmcnt(0)" ::: "memory");
    __builtin_amdgcn_s_barrier();

    // ---- W1 (s0,s1): K=64 from pe ----
    WKSTEP(S0, 2L*16384, S2, peA0, peB0, 1); KBAR4;
    WKSTEP(S1, 3L*16384, S3, peA1, peB1, 0); CONVERTL(0); KBAR4;

    // ---- 3x L1 hidden (phase 2) ----
#pragma unroll 1
    for (int l = 0; l < 3; ++l) {
        const long lb = 65536L + (long)l * 131072;   // stage byte base (s+2)
        const int bo = 256 + (l << 8);
        WKSTEP(S2, lb,            S0, actA[0], actB[0], 1); KBAR4;
        WKSTEP(S3, lb + 16384,    S1, actA[1], actB[1], 0); KBAR4;
        WKSTEP(S0, lb + 2*16384,  S2, actA[2], actB[2], 0); KBAR4;
        WKSTEP(S1, lb + 3*16384,  S3, actA[3], actB[3], 0); KBAR4;
        WKSTEP(S2, lb + 4*16384,  S0, actA[4], actB[4], 0); KBAR4;
        WKSTEP(S3, lb + 5*16384,  S1, actA[5], actB[5], 0); KBAR4;
        WKSTEP(S0, lb + 6*16384,  S2, actA[6], actB[6], 0); KBAR4;
        WKSTEP(S1, lb + 7*16384,  S3, actA[7], actB[7], 0); CONVERTL(bo); KBAR4;
    }

    // ---- W2 (s26..35): K=320 = 8 act ks + 2 pe ks ----
    WKSTEP(S2, 28L*16384, S0, actA[0], actB[0], 1); KBAR4;
    WKSTEP(S3, 29L*16384, S1, actA[1], actB[1], 0); KBAR4;
    WKSTEP(S0, 30L*16384, S2, actA[2], actB[2], 0); KBAR4;
    WKSTEP(S1, 31L*16384, S3, actA[3], actB[3], 0); KBAR4;
    WKSTEP(S2, 32L*16384, S0, actA[4], actB[4], 0); KBAR4;
    WKSTEP(S3, 33L*16384, S1, actA[5], actB[5], 0); KBAR4;
    WKSTEP(S0, 34L*16384, S2, actA[6], actB[6], 0); KBAR4;
    WKSTEP(S1, 35L*16384, S3, actA[7], actB[7], 0); KBAR4;
    WKSTEP(S2, 36L*16384, S0, peA0,    peB0,    0); KBAR4;
    WKSTEP(S3, 37L*16384, S1, peA1,    peB1,    0); CONVERTL(1024); KBAR4;

    // ---- 3x L2 hidden (phase 0) ----
#pragma unroll 1
    for (int l = 0; l < 3; ++l) {
        const long lb = (long)(38 + (l << 3)) * 16384;
        const int bo = 1280 + (l << 8);
        WKSTEP(S0, lb,            S2, actA[0], actB[0], 1); KBAR4;
        WKSTEP(S1, lb + 16384,    S3, actA[1], actB[1], 0); KBAR4;
        WKSTEP(S2, lb + 2*16384,  S0, actA[2], actB[2], 0); KBAR4;
        WKSTEP(S3, lb + 3*16384,  S1, actA[3], actB[3], 0); KBAR4;
        WKSTEP(S0, lb + 4*16384,  S2, actA[4], actB[4], 0); KBAR4;
        WKSTEP(S1, lb + 5*16384,  S3, actA[5], actB[5], 0); KBAR4;
        WKSTEP(S2, lb + 6*16384,  S0, actA[6], actB[6], 0); KBAR4;
        WKSTEP(S3, lb + 7*16384,  S1, actA[7], actB[7], 0); CONVERTL(bo); KBAR4;
    }
    // g in actA/actB. Ring state: s60 in S0 (landed), s61 in S1 (landed).

    // ---- sigma head (keep alpha in regs; store in epilogue) ----
    float alphaA, alphaB, srA, srB;
    {
        float sA = 0.f, sB = 0.f;
#pragma unroll
        for (int ks = 0; ks < 8; ++ks) {
            const s8 wv = *(const s8*)(wsB + (OFF_WSIG + ks * 32 + hi * 8) * 2);
#pragma unroll
            for (int j = 0; j < 8; ++j) {
                sA += bf2f(actA[ks][j]) * bf2f(wv[j]);
                sB += bf2f(actB[ks][j]) * bf2f(wv[j]);
            }
        }
        sA += __shfl_xor(sA, 16); sA += __shfl_xor(sA, 32);
        sB += __shfl_xor(sB, 16); sB += __shfl_xor(sB, 32);
        srA = sA + b_sigma[0]; srB = sB + b_sigma[0];
        alphaA = 1.f - __expf(-fmaxf(srA, 0.f) * STEP_LEN);
        alphaB = 1.f - __expf(-fmaxf(srB, 0.f) * STEP_LEN);
    }

    // ---- dir-encoding frags (26 dims + sigma at d=26, zero pad) ----
    s8 deA, deB;
    {
        float uA0 = (dir[gA*3+0] + 1.f) * 0.5f;
        float uA1 = (dir[gA*3+1] + 1.f) * 0.5f;
        float uA2 = (dir[gA*3+2] + 1.f) * 0.5f;
        float uB0 = (dir[gB*3+0] + 1.f) * 0.5f;
        float uB1 = (dir[gB*3+1] + 1.f) * 0.5f;
        float uB2 = (dir[gB*3+2] + 1.f) * 0.5f;
#pragma unroll
        for (int j = 0; j < 8; ++j) {
            int d = hi * 8 + j;
            float vA, vB;
            if (d < 13) {
                int c = d / 5, o = d % 5; float s = (float)(1 << o);
                vA = __sinf(((c == 0) ? uA0 : (c == 1) ? uA1 : uA2) * s);
                vB = __sinf(((c == 0) ? uB0 : (c == 1) ? uB1 : uB2) * s);
            } else if (d < 26) {
                int q = d - 13; int c = q / 5, o = q % 5; float s = (float)(1 << o);
                vA = __cosf(((c == 0) ? uA0 : (c == 1) ? uA1 : uA2) * s);
                vB = __cosf(((c == 0) ? uB0 : (c == 1) ? uB1 : uB2) * s);
            } else if (d == 26) {
                vA = srA; vB = srB;
            } else {
                vA = 0.f; vB = 0.f;
            }
            deA[j] = f2bf(vA); deB[j] = f2bf(vB);
        }
    }

    // ---- color layer 1: 4 C1G k-steps + de k-step (ring continues) ----
    STAGE4(62L*16384, S2); CKSTEP(S0, 0, 1); KBAR4;
    STAGE4(63L*16384, S3); CKSTEP(S1, 2, 0); KBAR4;
    STAGE4(64L*16384, S0); CKSTEP(S2, 4, 0); KBAR4;
    CKSTEP(S3, 6, 0); KBAR0;
    {   // de part from S0 (first 8KB of s64)
        __builtin_amdgcn_s_setprio(1);
#pragma unroll
        for (int nt = 0; nt < 8; ++nt) {
            const s8 w = *(const s8*)(S0 + nt * 1024 + lane * 16);
            acc[nt][0] = MFMA16(w, deA, acc[nt][0], 0, 0, 0);
            acc[nt][1] = MFMA16(w, deB, acc[nt][1], 0, 0, 0);
        }
        __builtin_amdgcn_s_setprio(0);
    }

    // ---- c1 frags (bias from LDS) ----
    s8 c1A[4], c1B[4];
#pragma unroll
    for (int nt = 0; nt < 8; ++nt) {
        const f32x4 b4 = *(const f32x4*)(biasL + ((2048 + nt * 16 + hi4) << 2));
#pragma unroll
        for (int r = 0; r < 4; ++r) {
            c1A[nt >> 1][((nt & 1) << 2) | r] = f2bf(fmaxf(acc[nt][0][r] + b4[r], 0.f));
            c1B[nt >> 1][((nt & 1) << 2) | r] = f2bf(fmaxf(acc[nt][1][r] + b4[r], 0.f));
        }
    }

    // ---- color layer 2 + sigmoid; all global stores here ----
#pragma unroll
    for (int ch = 0; ch < 3; ++ch) {
        float rA = 0.f, rB = 0.f;
#pragma unroll
        for (int ks = 0; ks < 4; ++ks) {
            const s8 wv = *(const s8*)(wsB + (OFF_WC2 + (ch * 4 + ks) * 32 + hi * 8) * 2);
#pragma unroll
            for (int j = 0; j < 8; ++j) {
                rA += bf2f(c1A[ks][j]) * bf2f(wv[j]);
                rB += bf2f(c1B[ks][j]) * bf2f(wv[j]);
            }
        }
        rA += __shfl_xor(rA, 16); rA += __shfl_xor(rA, 32);
        rB += __shfl_xor(rB, 16); rB += __shfl_xor(rB, 32);
        if (hi == 0) {
            out[gA * 3 + ch] = 1.f / (1.f + __expf(-(rA + b_c2[ch])));
            out[gB * 3 + ch] = 1.f / (1.f + __expf(-(rB + b_c2[ch])));
        }
    }
    if (hi == 0) {
        out[3 * N_PTS + gA] = alphaA;
        out[3 * N_PTS + gB] = alphaB;
    }
}

extern "C" void kernel_launch(void* const* d_in, const int* in_sizes, int n_in,
                              void* d_out, int out_size, void* d_ws, size_t ws_size,
                              hipStream_t stream) {
    const float* position = (const float*)d_in[0];
    const float* direction = (const float*)d_in[1];
    const float* w1_in = (const float*)d_in[2];
    const float* b1_in = (const float*)d_in[3];
    const float* w1_h  = (const float*)d_in[4];
    const float* b1_h  = (const float*)d_in[5];
    const float* w2_in = (const float*)d_in[6];
    const float* b2_in = (const float*)d_in[7];
    const float* w2_h  = (const float*)d_in[8];
    const float* b2_h  = (const float*)d_in[9];
    const float* w_sigma = (const float*)d_in[10];
    const float* b_sigma = (const float*)d_in[11];
    const float* w_c1  = (const float*)d_in[12];
    const float* b_c1  = (const float*)d_in[13];
    const float* w_c2  = (const float*)d_in[14];
    const float* b_c2  = (const float*)d_in[15];
    float* out = (float*)d_out;
    __hip_bfloat16* ws = (__hip_bfloat16*)d_ws;

    prep_weights<<<(WS_ELEMS + 255) / 256, 256, 0, stream>>>(
        w1_in, w1_h, w2_in, w2_h, w_c1, w_sigma, w_c2, ws);

    nerf_fused<<<N_PTS / 128, 256, 0, stream>>>(
        position, direction, ws,
        b1_in, b1_h, b2_in, b2_h,
        b_sigma, b_c1, b_c2, out);
}